// Round 1
// baseline (374.953 us; speedup 1.0000x reference)
//
#include <hip/hip_runtime.h>

// out[b,c,y,x] = sum_{dy,dx in [0,13)} aff[b, dy*13+dx, y, x] * in2_zp[b, c, y+dy-6, x+dx-6]
// B=4 C=64 H=W=192 D=169.
//
// Structure: one block per (b, y) row. 192 threads = 48 x-groups (4 x each) x 4
// c-chunks (16 channels each). Outer loop over dy stages one zero-padded in2 row
// (all 64 channels, width 208) into LDS; threads hold 13 aff float4s in regs
// (reused across 16 channels) and read 20-float windows via ds_read_b128.
// acc[16][4] in VGPRs; fully unrolled 52-FMA inner loop per channel.

#define KD   6
#define WIN  13
#define ND   169
#define NB   4
#define NC   64
#define NH   192
#define NW   192
#define PADW 208   // 8 zero | 192 data | 8 zero  (keeps ds_read_b128 16B-aligned)
#define CB   16    // channels per thread
#define XB   4     // x outputs per thread
#define NXG  (NW / XB)      // 48
#define NTH  (NXG * (NC/CB)) // 192 threads = 3 waves

__global__ __launch_bounds__(NTH, 3)
void mxassemble(const float* __restrict__ aff,
                const float* __restrict__ in2,
                float* __restrict__ out) {
    __shared__ float lds[NC * PADW];   // 53248 B = 52 KiB -> 3 blocks/CU

    const int y  = blockIdx.x;
    const int b  = blockIdx.y;
    const int t  = threadIdx.x;
    const int xg = t % NXG;      // 0..47
    const int cc = t / NXG;      // 0..3
    const int x0 = xg * XB;
    const int c0 = cc * CB;

    // Zero the pad columns once (interior is overwritten every dy iteration,
    // pads are never touched again).
    for (int i = t; i < NC * 4; i += NTH) {
        const int c = i >> 2;
        const int q = i & 3;
        const int col = (q < 2) ? (4 * q) : (192 + 4 * q); // 0,4 | 200,204
        *(float4*)&lds[c * PADW + col] = make_float4(0.f, 0.f, 0.f, 0.f);
    }

    float acc[CB][XB];
#pragma unroll
    for (int c = 0; c < CB; ++c)
#pragma unroll
        for (int j = 0; j < XB; ++j) acc[c][j] = 0.f;

    const float* in2_b = in2 + (size_t)b * NC * NH * NW;
    const float* aff_b = aff + (size_t)b * ND * NH * NW;

    for (int dy = 0; dy < WIN; ++dy) {
        const int r = y + dy - KD;
        const bool valid = (r >= 0) && (r < NH);   // block-uniform

        __syncthreads();   // previous iteration's readers are done
        if (valid) {
            // Stage in2[b, :, r, :] -> LDS (coalesced float4s).
            for (int i = t; i < (NC * NW) / 4; i += NTH) {
                const int c  = i / (NW / 4);
                const int xc = (i % (NW / 4)) * 4;
                const float4 v =
                    *(const float4*)&in2_b[((size_t)c * NH + r) * NW + xc];
                *(float4*)&lds[c * PADW + 8 + xc] = v;
            }
        }
        __syncthreads();
        if (!valid) continue;   // padded row contributes zero

        // aff[b, dy*13+dx, y, x0..x0+3] for dx=0..12 -> 52 regs, reused 16x.
        float A[WIN][XB];
        {
            const float* ab = aff_b + ((size_t)(dy * WIN) * NH + y) * NW + x0;
#pragma unroll
            for (int dx = 0; dx < WIN; ++dx) {
                const float4 v = *(const float4*)&ab[(size_t)dx * NH * NW];
                A[dx][0] = v.x; A[dx][1] = v.y; A[dx][2] = v.z; A[dx][3] = v.w;
            }
        }

#pragma unroll
        for (int c = 0; c < CB; ++c) {
            // Window covers padded cols [x0, x0+20) == real cols [x0-8, x0+12);
            // needed cols are [x0-6, x0+9] -> w[dx+j+2].
            float w[20];
            const float* wp = &lds[(c0 + c) * PADW + x0];
#pragma unroll
            for (int k = 0; k < 5; ++k) {
                const float4 v = *(const float4*)&wp[4 * k];
                w[4*k+0] = v.x; w[4*k+1] = v.y; w[4*k+2] = v.z; w[4*k+3] = v.w;
            }
#pragma unroll
            for (int dx = 0; dx < WIN; ++dx)
#pragma unroll
                for (int j = 0; j < XB; ++j)
                    acc[c][j] = fmaf(A[dx][j], w[dx + j + 2], acc[c][j]);
        }
    }

    float* ob = out + (((size_t)b * NC + c0) * NH + y) * NW + x0;
#pragma unroll
    for (int c = 0; c < CB; ++c) {
        *(float4*)&ob[(size_t)c * NH * NW] =
            make_float4(acc[c][0], acc[c][1], acc[c][2], acc[c][3]);
    }
}

extern "C" void kernel_launch(void* const* d_in, const int* in_sizes, int n_in,
                              void* d_out, int out_size, void* d_ws, size_t ws_size,
                              hipStream_t stream) {
    const float* aff = (const float*)d_in[0];   // [4,169,192,192] f32
    const float* in2 = (const float*)d_in[1];   // [4, 64,192,192] f32
    float* outp = (float*)d_out;                // [4, 64,192,192] f32
    dim3 grid(NH, NB);
    dim3 block(NTH);
    hipLaunchKernelGGL(mxassemble, grid, block, 0, stream, aff, in2, outp);
}

// Round 2
// 358.008 us; speedup vs baseline: 1.0473x; 1.0473x over previous
//
#include <hip/hip_runtime.h>

// out[b,c,y,x] = sum_{dy,dx in [0,13)} aff[b, dy*13+dx, y, x] * in2_zp[b, c, y+dy-6, x+dx-6]
// B=4 C=64 H=W=192 D=169.
//
// Round 2: XB=8 (halves LDS-read amplification: 20 floats -> 8 outputs),
// CB=4, channel-split blocks (32 ch each, 27 KB LDS), PADW=212 (odd*4 mod 32
// bank stagger), pad-left=6 so the 5 window ds_read_b128 stay 16B-aligned.
// amdgpu_waves_per_eu(2,3) pinned: round 1's VGPR_Count=84 + WRITE_SIZE=185MB
// showed the compiler chasing 6 waves/EU and spilling acc/A to scratch.

#define KD   6
#define WIN  13
#define ND   169
#define NB   4
#define NC   64
#define NH   192
#define NW   192
#define PADW 212   // 6 zero | 192 data | 14 zero; 212 % 32 = 20 (bank stagger)
#define NCH  32    // channels staged per block
#define CB   4     // channels per thread
#define XB   8     // x outputs per thread
#define NXG  (NW / XB)          // 24 x-groups
#define NCC  (NCH / CB)         // 8 c-chunks
#define NTH  (NXG * NCC)        // 192 threads = 3 waves

__global__ __launch_bounds__(NTH)
__attribute__((amdgpu_waves_per_eu(2, 3)))
void mxassemble(const float* __restrict__ aff,
                const float* __restrict__ in2,
                float* __restrict__ out) {
    __shared__ float lds[NCH * PADW];   // 27136 B

    const int y  = blockIdx.x;
    const int h  = blockIdx.y;          // channel half: 0 or 1
    const int b  = blockIdx.z;
    const int t  = threadIdx.x;
    const int xg = t % NXG;             // 0..23
    const int cc = t / NXG;             // 0..7
    const int x0 = xg * XB;
    const int cl0 = cc * CB;            // local channel base within the half

    // Zero pad columns once: cols [0,6) and [198,212) of each row.
    for (int i = t; i < NCH * 20; i += NTH) {
        const int cl = i / 20;
        const int q  = i % 20;
        const int col = (q < 6) ? q : (192 + q);  // 0..5 | 198..211
        lds[cl * PADW + col] = 0.f;
    }

    float acc[CB][XB];
#pragma unroll
    for (int c = 0; c < CB; ++c)
#pragma unroll
        for (int j = 0; j < XB; ++j) acc[c][j] = 0.f;

    const float* in2_b = in2 + ((size_t)b * NC + (size_t)h * NCH) * NH * NW;
    const float* aff_b = aff + (size_t)b * ND * NH * NW;

    for (int dy = 0; dy < WIN; ++dy) {
        const int r = y + dy - KD;
        const bool valid = (r >= 0) && (r < NH);   // block-uniform

        __syncthreads();   // previous iteration's readers done
        if (valid) {
            // Stage in2[b, h*32 + cl, r, :] -> LDS. float4 global loads,
            // 2x float2 LDS writes (dst offset 6+xc is only 8B-aligned).
            for (int i = t; i < (NCH * NW) / 4; i += NTH) {
                const int cl = i / (NW / 4);
                const int xc = (i % (NW / 4)) * 4;
                const float4 v =
                    *(const float4*)&in2_b[((size_t)cl * NH + r) * NW + xc];
                float* dst = &lds[cl * PADW + 6 + xc];
                *(float2*)&dst[0] = make_float2(v.x, v.y);
                *(float2*)&dst[2] = make_float2(v.z, v.w);
            }
        }
        __syncthreads();
        if (!valid) continue;   // zero-padded row contributes nothing

        // aff[b, dy*13+dx, y, x0..x0+7], dx=0..12 -> 104 regs, reused 4x.
        float A[WIN][XB];
        {
            const float* ab = aff_b + ((size_t)(dy * WIN) * NH + y) * NW + x0;
#pragma unroll
            for (int dx = 0; dx < WIN; ++dx) {
                const float4 v0 = *(const float4*)&ab[(size_t)dx * NH * NW];
                const float4 v1 = *(const float4*)&ab[(size_t)dx * NH * NW + 4];
                A[dx][0] = v0.x; A[dx][1] = v0.y; A[dx][2] = v0.z; A[dx][3] = v0.w;
                A[dx][4] = v1.x; A[dx][5] = v1.y; A[dx][6] = v1.z; A[dx][7] = v1.w;
            }
        }

#pragma unroll
        for (int c = 0; c < CB; ++c) {
            // Window = padded cols [x0, x0+20); tap (j,dx) reads w[j+dx].
            float w[20];
            const float* wp = &lds[(cl0 + c) * PADW + x0];
#pragma unroll
            for (int k = 0; k < 5; ++k) {
                const float4 v = *(const float4*)&wp[4 * k];
                w[4*k+0] = v.x; w[4*k+1] = v.y; w[4*k+2] = v.z; w[4*k+3] = v.w;
            }
#pragma unroll
            for (int dx = 0; dx < WIN; ++dx)
#pragma unroll
                for (int j = 0; j < XB; ++j)
                    acc[c][j] = fmaf(A[dx][j], w[j + dx], acc[c][j]);
        }
    }

    float* ob = out + (((size_t)(b * NC + h * NCH + cl0) * NH) + y) * NW + x0;
#pragma unroll
    for (int c = 0; c < CB; ++c) {
        *(float4*)&ob[(size_t)c * NH * NW + 0] =
            make_float4(acc[c][0], acc[c][1], acc[c][2], acc[c][3]);
        *(float4*)&ob[(size_t)c * NH * NW + 4] =
            make_float4(acc[c][4], acc[c][5], acc[c][6], acc[c][7]);
    }
}

extern "C" void kernel_launch(void* const* d_in, const int* in_sizes, int n_in,
                              void* d_out, int out_size, void* d_ws, size_t ws_size,
                              hipStream_t stream) {
    const float* aff = (const float*)d_in[0];   // [4,169,192,192] f32
    const float* in2 = (const float*)d_in[1];   // [4, 64,192,192] f32
    float* outp = (float*)d_out;                // [4, 64,192,192] f32
    dim3 grid(NH, NC / NCH, NB);
    dim3 block(NTH);
    hipLaunchKernelGGL(mxassemble, grid, block, 0, stream, aff, in2, outp);
}